// Round 8
// baseline (95.881 us; speedup 1.0000x reference)
//
#include <hip/hip_runtime.h>

typedef short v8s __attribute__((ext_vector_type(8)));
typedef float v4f __attribute__((ext_vector_type(4)));
typedef unsigned short u16;
typedef unsigned short usv4 __attribute__((ext_vector_type(4)));

constexpr int PSTR = 72;           // ushorts per plane row (144 B, 16B-aligned)
constexpr int PSZ  = 64 * PSTR;    // ushorts per plane
constexpr int MSZ  = 2 * PSZ;      // hi plane + lo plane per matrix

#define MFMA16 __builtin_amdgcn_mfma_f32_16x16x32_bf16

__device__ __forceinline__ v8s ldf(const u16* plane, int row, int kc) {
    return *(const v8s*)&plane[row * PSTR + kc];
}

// fp32 -> (hi bf16 bits = truncated top16, lo bf16 bits = RNE of exact remainder)
__device__ __forceinline__ void split2(float x, u16& h, u16& l) {
    unsigned xb = __builtin_bit_cast(unsigned, x);
    h = (u16)(xb >> 16);
    float lof = x - __builtin_bit_cast(float, xb & 0xffff0000u);   // exact
    unsigned lb = __builtin_bit_cast(unsigned, lof) + 0x8000u;
    l = (u16)(lb >> 16);
}
__device__ __forceinline__ float join2(u16 h, u16 l) {
    return __builtin_bit_cast(float, (unsigned)h << 16)
         + __builtin_bit_cast(float, (unsigned)l << 16);
}

// acc[t]: rows [rb,rb+16) x cols [cb+16t, cb+16t+16) of P * Q^T  (K=64, split bf16)
__device__ __forceinline__ void hstrip(const u16* __restrict__ P,
                                       const u16* __restrict__ Q,
                                       int rb, int cb, int lane, v4f acc[2]) {
    const int nh = lane & 15, qd = lane >> 4;
    const int ar = rb + nh;
    v8s ah0 = ldf(P, ar, qd * 8),       ah1 = ldf(P, ar, 32 + qd * 8);
    v8s al0 = ldf(P + PSZ, ar, qd * 8), al1 = ldf(P + PSZ, ar, 32 + qd * 8);
    #pragma unroll
    for (int t = 0; t < 2; ++t) {
        const int br = cb + 16 * t + nh;
        v8s bh0 = ldf(Q, br, qd * 8),       bh1 = ldf(Q, br, 32 + qd * 8);
        v8s bl0 = ldf(Q + PSZ, br, qd * 8), bl1 = ldf(Q + PSZ, br, 32 + qd * 8);
        v4f a0 = {0, 0, 0, 0}, a1 = {0, 0, 0, 0};
        a0 = MFMA16(ah0, bh0, a0, 0, 0, 0);
        a1 = MFMA16(ah0, bl0, a1, 0, 0, 0);
        a1 = MFMA16(al0, bh0, a1, 0, 0, 0);
        a0 = MFMA16(ah1, bh1, a0, 0, 0, 0);
        a1 = MFMA16(ah1, bl1, a1, 0, 0, 0);
        a1 = MFMA16(al1, bh1, a1, 0, 0, 0);
        acc[t] = a0 + a1;
    }
}

// store split value
__device__ __forceinline__ void st2(u16* M, int row, int col, float v) {
    u16 h, l; split2(v, h, l);
    M[row * PSTR + col] = h;
    M[PSZ + row * PSTR + col] = l;
}

// dual store: rows into Dr, transposed (b64 per plane) into Dt
__device__ __forceinline__ void st_dual(u16* Dr, u16* Dt, int rb, int cb,
                                        int lane, const v4f acc[2]) {
    const int nh = lane & 15, qd = lane >> 4;
    #pragma unroll
    for (int t = 0; t < 2; ++t) {
        const int col = cb + 16 * t + nh;
        usv4 h4, l4;
        #pragma unroll
        for (int e = 0; e < 4; ++e) {
            const int row = rb + 4 * qd + e;
            u16 h, l; split2(acc[t][e], h, l);
            Dr[row * PSTR + col] = h;
            Dr[PSZ + row * PSTR + col] = l;
            h4[e] = h; l4[e] = l;
        }
        *(usv4*)&Dt[col * PSTR + rb + 4 * qd] = h4;
        *(usv4*)&Dt[PSZ + col * PSTR + rb + 4 * qd] = l4;
    }
}

__launch_bounds__(512)
__global__ void krylov_kernel(const float* __restrict__ A,
                              const float* __restrict__ Bv,
                              const float* __restrict__ Cv,
                              const float* __restrict__ logdt,
                              float* __restrict__ out)
{
    const int h    = blockIdx.x;
    const int tid  = threadIdx.x;
    const int lane = tid & 63;
    const int w    = tid >> 6;
    const int nh   = lane & 15, qd = lane >> 4;
    const int rb   = 16 * (w >> 1), cb = 32 * (w & 1);   // this wave's unit

    __shared__ __align__(16) u16 ARENA[6 * MSZ];   // 6 matrices x (hi+lo planes)
    __shared__ float Bl[64], tmv[64];

    u16* M0 = ARENA;            // S        -> X-pong
    u16* M1 = ARENA + 1 * MSZ;  // D        -> X-ping
    u16* M2 = ARENA + 2 * MSZ;  // I+D -> T -> XT-pong
    u16* M3 = ARENA + 3 * MSZ;  // u        -> XT-ping
    u16* M4 = ARENA + 4 * MSZ;  // I+D2     -> Vt
    u16* M5 = ARENA + 5 * MSZ;  // Ut

    const float dt  = expf(logdt[h]);
    const float cc  = 0.5f * dt;
    const float al  = 1.0f + 0.5f * cc;
    const float sd2 = (cc * cc) / (al * al);   // D = sd2*S^2 = -sd2*(S S^T)
    const float c1  = 2.0f / al;               // X = c1*T + c2*(S T) - I
    const float c2  = 2.0f * cc / (al * al);

    const float* Ah = A + (size_t)h * 4096;

    // ---- P0: pack S = A + 0.5I planes -> M0; B -> Bl; Ut row0 = C -> M5 ----
    {
        const int r0 = tid >> 3;            // 0..63
        const int c0 = (tid & 7) * 8;       // 0..56
        float xv[8];
        *(float4*)&xv[0] = *(const float4*)(Ah + r0 * 64 + c0);
        *(float4*)&xv[4] = *(const float4*)(Ah + r0 * 64 + c0 + 4);
        const int dj = r0 - c0;
        if (dj >= 0 && dj < 8) xv[dj] += 0.5f;
        v8s vh, vl;
        #pragma unroll
        for (int j = 0; j < 8; ++j) {
            u16 hh, ll; split2(xv[j], hh, ll);
            vh[j] = (short)hh; vl[j] = (short)ll;
        }
        *(v8s*)&M0[r0 * PSTR + c0] = vh;
        *(v8s*)&M0[PSZ + r0 * PSTR + c0] = vl;
        if (tid < 64) Bl[tid] = Bv[h * 64 + tid];
        else if (tid < 128) st2(M5, 0, tid - 64, Cv[h * 64 + (tid - 64)]);
    }
    __syncthreads();

    // ---- P1: D = -sd2*(S*S^T) -> M1 ; I+D -> M2 ----
    {
        v4f a[2]; hstrip(M0, M0, rb, cb, lane, a);
        #pragma unroll
        for (int t = 0; t < 2; ++t)
            #pragma unroll
            for (int e = 0; e < 4; ++e) {
                const int row = rb + 4 * qd + e, col = cb + 16 * t + nh;
                float dv = -sd2 * a[t][e];
                st2(M1, row, col, dv);
                st2(M2, row, col, dv + (row == col ? 1.0f : 0.0f));
            }
    }
    __syncthreads();
    // ---- P2 (16 units): u = D*(I+D) -> M3 ; I+D2 = I + D*D -> M4 ----
    {
        v4f a[2]; hstrip(M1, M2, rb, cb, lane, a);
        #pragma unroll
        for (int t = 0; t < 2; ++t)
            #pragma unroll
            for (int e = 0; e < 4; ++e)
                st2(M3, rb + 4 * qd + e, cb + 16 * t + nh, a[t][e]);
        v4f b[2]; hstrip(M1, M1, rb, cb, lane, b);
        #pragma unroll
        for (int t = 0; t < 2; ++t)
            #pragma unroll
            for (int e = 0; e < 4; ++e) {
                const int row = rb + 4 * qd + e, col = cb + 16 * t + nh;
                st2(M4, row, col, b[t][e] + (row == col ? 1.0f : 0.0f));
            }
    }
    __syncthreads();
    // ---- P3: T = I + u*(I+D2) -> M2 ----
    {
        v4f a[2]; hstrip(M3, M4, rb, cb, lane, a);
        #pragma unroll
        for (int t = 0; t < 2; ++t)
            #pragma unroll
            for (int e = 0; e < 4; ++e) {
                const int row = rb + 4 * qd + e, col = cb + 16 * t + nh;
                st2(M2, row, col, a[t][e] + (row == col ? 1.0f : 0.0f));
            }
    }
    __syncthreads();
    // ---- P4: SH = S*T; X = c1*T + c2*SH - I -> M1 ; XT (elementwise) -> M3 ----
    {
        v4f a[2]; hstrip(M0, M2, rb, cb, lane, a);
        #pragma unroll
        for (int t = 0; t < 2; ++t)
            #pragma unroll
            for (int e = 0; e < 4; ++e) {
                const int row = rb + 4 * qd + e, col = cb + 16 * t + nh;
                float tv = join2(M2[row * PSTR + col], M2[PSZ + row * PSTR + col]);
                float base = c1 * tv - (row == col ? 1.0f : 0.0f);
                float sv   = c2 * a[t][e];
                st2(M1, row, col, base + sv);
                st2(M3, row, col, base - sv);
            }
    }
    __syncthreads();

    // ---- L0: sq (waves 0-3, 2 units each): (X^2)^T = XT*X^T, dual-store.
    //          wave 4: seeds v0 = cc*(X*B + B), v1 = X*v0 -> Vt(M4) rows 0,1 ----
    {
        if (w < 4) {
            v4f a[2]; hstrip(M3, M1, 16 * w, 0, lane, a);
            st_dual(M2, M0, 16 * w, 0, lane, a);
            v4f b[2]; hstrip(M3, M1, 16 * w, 32, lane, b);
            st_dual(M2, M0, 16 * w, 32, lane, b);
        } else if (w == 4) {
            float acc1 = 0.f;
            #pragma unroll
            for (int m = 0; m < 8; ++m) {
                v8s xh = ldf(M1, lane, m * 8);
                v8s xl = ldf(M1 + PSZ, lane, m * 8);
                #pragma unroll
                for (int j = 0; j < 8; ++j)
                    acc1 = fmaf(join2((u16)xh[j], (u16)xl[j]), Bl[m * 8 + j], acc1);
            }
            float v0 = cc * (acc1 + Bl[lane]);
            tmv[lane] = v0;
            __threadfence_block();
            float acc2 = 0.f;
            #pragma unroll
            for (int m = 0; m < 8; ++m) {
                v8s xh = ldf(M1, lane, m * 8);
                v8s xl = ldf(M1 + PSZ, lane, m * 8);
                #pragma unroll
                for (int j = 0; j < 8; ++j)
                    acc2 = fmaf(join2((u16)xh[j], (u16)xl[j]), tmv[m * 8 + j], acc2);
            }
            st2(M4, 0, lane, v0);
            st2(M4, 1, lane, acc2);
        }
    }
    __syncthreads();

    // ---- ladder p=1..11. pX = X_p = dA^(2^p). V-phases p<6, U-phases p>=6.
    //  sq (p<11): V: (X^2)^T = hstrip(XT, X) dual-> (XTn rows, Xn transp)
    //             U:  X^2    = hstrip(X, XT) dual-> (Xn rows, XTn transp)
    //  dbl: V: Vt[k+j] = hstrip(Vt, X) row j  (k = 2^p, j<k)
    //       U: Ut[k+j] = hstrip(Ut, XT) row j (k = 2^(p-6))
    u16 *pX = M0, *pXT = M2, *pXn = M1, *pXTn = M3;
    #pragma unroll 1
    for (int p = 1; p < 12; ++p) {
        const bool isV = (p < 6);
        const int  k   = 1 << (isV ? p : p - 6);
        if (p < 11) {
            v4f a[2];
            if (isV) { hstrip(pXT, pX, rb, cb, lane, a); st_dual(pXTn, pXn, rb, cb, lane, a); }
            else     { hstrip(pX, pXT, rb, cb, lane, a); st_dual(pXn, pXTn, rb, cb, lane, a); }
        }
        const int ndb = (k <= 16) ? 2 : 4;
        if (w < ndb) {
            const int sr = (k <= 16) ? 0 : (w >> 1);
            const int ch = (k <= 16) ? w : (w & 1);
            u16* Kt = isV ? M4 : M5;
            const u16* Q = isV ? pX : pXT;
            v4f a[2]; hstrip(Kt, Q, 16 * sr, 32 * ch, lane, a);
            #pragma unroll
            for (int t = 0; t < 2; ++t)
                #pragma unroll
                for (int e = 0; e < 4; ++e) {
                    const int j = 16 * sr + 4 * qd + e;
                    if (j < k) st2(Kt, k + j, 32 * ch + 16 * t + nh, a[t][e]);
                }
        }
        __syncthreads();
        if (p < 11) {
            u16* s = pX;  pX  = pXn;  pXn  = s;
            s = pXT; pXT = pXTn; pXTn = s;
        }
    }

    // ---- final: out[h][64q + r] = sum_n Ut[q][n] * Vt[r][n] ----
    {
        v4f a[2]; hstrip(M5, M4, rb, cb, lane, a);
        float* oh = out + (size_t)h * 4096;
        #pragma unroll
        for (int t = 0; t < 2; ++t)
            #pragma unroll
            for (int e = 0; e < 4; ++e)
                oh[(rb + 4 * qd + e) * 64 + cb + 16 * t + nh] = a[t][e];
    }
}

extern "C" void kernel_launch(void* const* d_in, const int* in_sizes, int n_in,
                              void* d_out, int out_size, void* d_ws, size_t ws_size,
                              hipStream_t stream) {
    const float* A  = (const float*)d_in[0];
    const float* B  = (const float*)d_in[1];
    const float* C  = (const float*)d_in[2];
    const float* ld = (const float*)d_in[3];
    float* out = (float*)d_out;
    const int H = in_sizes[3];   // 256 heads
    krylov_kernel<<<H, 512, 0, stream>>>(A, B, C, ld, out);
}

// Round 9
// 81.996 us; speedup vs baseline: 1.1693x; 1.1693x over previous
//
#include <hip/hip_runtime.h>

constexpr int STRU = 68;   // row stride in u32 (272 B; rows 16B-aligned)

typedef short v8s __attribute__((ext_vector_type(8)));
typedef float v4f __attribute__((ext_vector_type(4)));

// fp32 -> packed (bf16_hi << 16) | bf16_lo. hi = truncated, lo = Dekker remainder.
__device__ __forceinline__ unsigned packhl(float x) {
    unsigned xb = __builtin_bit_cast(unsigned, x);
    unsigned hb = xb & 0xffff0000u;
    float lof = x - __builtin_bit_cast(float, hb);           // exact
    unsigned lb = __builtin_bit_cast(unsigned, lof) + 0x8000u;
    return __builtin_amdgcn_perm(xb, lb, 0x07060302u);
}

__device__ __forceinline__ float unpackf(unsigned v) {
    float h = __builtin_bit_cast(float, v & 0xffff0000u);
    float l = __builtin_bit_cast(float, v << 16);
    return h + l;
}

// 8 contiguous packed u32 (one MFMA k-fragment of a row) -> hi/lo bf16x8
__device__ __forceinline__ void load_frag(const unsigned* p, v8s& hi, v8s& lo) {
    uint4 a = *(const uint4*)p;
    uint4 b = *(const uint4*)(p + 4);
    uint4 hw, lw;
    hw.x = __builtin_amdgcn_perm(a.y, a.x, 0x07060302u);
    hw.y = __builtin_amdgcn_perm(a.w, a.z, 0x07060302u);
    hw.z = __builtin_amdgcn_perm(b.y, b.x, 0x07060302u);
    hw.w = __builtin_amdgcn_perm(b.w, b.z, 0x07060302u);
    lw.x = __builtin_amdgcn_perm(a.y, a.x, 0x05040100u);
    lw.y = __builtin_amdgcn_perm(a.w, a.z, 0x05040100u);
    lw.z = __builtin_amdgcn_perm(b.y, b.x, 0x05040100u);
    lw.w = __builtin_amdgcn_perm(b.w, b.z, 0x05040100u);
    hi = __builtin_bit_cast(v8s, hw);
    lo = __builtin_bit_cast(v8s, lw);
}

#define MFMA16 __builtin_amdgcn_mfma_f32_16x16x32_bf16

// Row-strip of D = P * Q^T: rows [rb, rb+16), col-tiles [t0, t0+NT).
// A-fragment loaded ONCE, shared across NT tiles (verified R7).
template<int NT>
__device__ __forceinline__ void strip_acc(const unsigned* __restrict__ P,
                                          const unsigned* __restrict__ Q,
                                          int rb, int t0, int lane, v4f* acc) {
    const int nh = lane & 15, qd = lane >> 4;
    v8s ah[2], al[2];
    load_frag(P + (rb + nh) * STRU + qd * 8,      ah[0], al[0]);
    load_frag(P + (rb + nh) * STRU + 32 + qd * 8, ah[1], al[1]);
    v8s bh[NT][2], bl[NT][2];
    #pragma unroll
    for (int t = 0; t < NT; ++t) {
        const unsigned* qr = Q + ((t0 + t) * 16 + nh) * STRU;
        load_frag(qr + qd * 8,      bh[t][0], bl[t][0]);
        load_frag(qr + 32 + qd * 8, bh[t][1], bl[t][1]);
    }
    #pragma unroll
    for (int t = 0; t < NT; ++t) {
        v4f a0 = {0, 0, 0, 0}, a1 = {0, 0, 0, 0};
        #pragma unroll
        for (int kk = 0; kk < 2; ++kk) {
            a0 = MFMA16(ah[kk], bh[t][kk], a0, 0, 0, 0);
            a1 = MFMA16(ah[kk], bl[t][kk], a1, 0, 0, 0);
            a1 = MFMA16(al[kk], bh[t][kk], a1, 0, 0, 0);
        }
        acc[t] = a0 + a1;
    }
}

__launch_bounds__(1024)
__global__ void krylov_kernel(const float* __restrict__ A,
                              const float* __restrict__ Bv,
                              const float* __restrict__ Cv,
                              const float* __restrict__ logdt,
                              float* __restrict__ out)
{
    const int h    = blockIdx.x;
    const int tid  = threadIdx.x;
    const int lane = tid & 63;
    const int w    = tid >> 6;                 // 0..15
    const int nh   = lane & 15, qd = lane >> 4;
    const int rb1  = 16 * (w >> 2), t01 = w & 3;         // 16-unit map (16x16)
    const int rb2  = 16 * (w >> 1), t02 = 2 * (w & 1);   // 8-unit map (16x32), w<8

    // B0: S -> XT-pong. B1: X-ping -> X-pong(swap). B2: I+D^2 -> XT-ping.
    // B3: D -> X_1 rows. B4: T0 -> T -> Vt. B5: u -> Ut.
    __shared__ __align__(16) unsigned B0[64 * STRU], B1[64 * STRU], B2[64 * STRU],
                                      B3[64 * STRU], B4[64 * STRU], B5[64 * STRU];
    __shared__ float Bl[64], Cl[64], tmv[64];

    const float dt  = expf(logdt[h]);
    const float cc  = 0.5f * dt;
    const float al  = 1.0f + 0.5f * cc;
    const float sd2 = (cc * cc) / (al * al);   // D = -sd2*(S S^T)
    const float c1  = 2.0f / al;               // X = c1*T + c2*(S T) - I
    const float c2  = 2.0f * cc / (al * al);

    const float* Ah = A + (size_t)h * 4096;

    // ---- P0: pack S = A + 0.5I -> B0; load B, C ----
    {
        const int rr = tid >> 4, c0 = (tid & 15) * 4;
        float4 v = *(const float4*)(Ah + rr * 64 + c0);
        if (rr == c0 + 0) v.x += 0.5f;
        if (rr == c0 + 1) v.y += 0.5f;
        if (rr == c0 + 2) v.z += 0.5f;
        if (rr == c0 + 3) v.w += 0.5f;
        uint4 pk = make_uint4(packhl(v.x), packhl(v.y), packhl(v.z), packhl(v.w));
        *(uint4*)&B0[rr * STRU + c0] = pk;
        if (tid < 64) Bl[tid] = Bv[h * 64 + tid];
        else if (tid < 128) Cl[tid - 64] = Cv[h * 64 + (tid - 64)];
    }
    __syncthreads();

    // ---- P1 (16 units): D = -sd2*(S*S^T) -> B3 ; T0 = D + I -> B4 ----
    {
        v4f a[1]; strip_acc<1>(B0, B0, rb1, t01, lane, a);
        #pragma unroll
        for (int e = 0; e < 4; ++e) {
            const int row = rb1 + 4 * qd + e, col = t01 * 16 + nh;
            float dv = -sd2 * a[0][e];
            B3[row * STRU + col] = packhl(dv);
            B4[row * STRU + col] = packhl(dv + (row == col ? 1.0f : 0.0f));
        }
    }
    __syncthreads();
    // ---- P2 (2 products, all 16 waves): u = D*T0 -> B5 ; I+D^2 -> B2 ----
    if (w < 8) {
        v4f a[2]; strip_acc<2>(B3, B4, rb2, t02, lane, a);
        #pragma unroll
        for (int t = 0; t < 2; ++t)
            #pragma unroll
            for (int e = 0; e < 4; ++e)
                B5[(rb2 + 4 * qd + e) * STRU + (t02 + t) * 16 + nh] = packhl(a[t][e]);
    } else {
        const int rbu = 16 * ((w - 8) >> 1), tcu = 2 * ((w - 8) & 1);
        v4f a[2]; strip_acc<2>(B3, B3, rbu, tcu, lane, a);
        #pragma unroll
        for (int t = 0; t < 2; ++t)
            #pragma unroll
            for (int e = 0; e < 4; ++e) {
                const int row = rbu + 4 * qd + e, col = (tcu + t) * 16 + nh;
                B2[row * STRU + col] = packhl(a[t][e] + (row == col ? 1.0f : 0.0f));
            }
    }
    __syncthreads();
    // ---- P3 (16 units): T = I + u*(I+D^2) -> B4 ----
    {
        v4f a[1]; strip_acc<1>(B5, B2, rb1, t01, lane, a);
        #pragma unroll
        for (int e = 0; e < 4; ++e) {
            const int row = rb1 + 4 * qd + e, col = t01 * 16 + nh;
            B4[row * STRU + col] = packhl(a[0][e] + (row == col ? 1.0f : 0.0f));
        }
    }
    __syncthreads();
    // ---- P4 (16 units): SH = S*T; X = c1*T + c2*SH - I -> B1, XT -> B2 ----
    {
        v4f a[1]; strip_acc<1>(B0, B4, rb1, t01, lane, a);
        #pragma unroll
        for (int e = 0; e < 4; ++e) {
            const int row = rb1 + 4 * qd + e, col = t01 * 16 + nh;
            float tv = unpackf(B4[row * STRU + col]);
            float base = c1 * tv - (row == col ? 1.0f : 0.0f);
            float sv   = c2 * a[0][e];
            B1[row * STRU + col] = packhl(base + sv);
            B2[row * STRU + col] = packhl(base - sv);
        }
    }
    __syncthreads();
    // ---- L0: sq X -> X_1 (w0-7: rows->B3, transp->B0); w8: seed v0,v1; w9: C ----
    {
        if (w < 8) {
            v4f a[2]; strip_acc<2>(B1, B2, rb2, t02, lane, a);
            #pragma unroll
            for (int t = 0; t < 2; ++t) {
                uint4 tp;
                #pragma unroll
                for (int e = 0; e < 4; ++e) {
                    unsigned pk = packhl(a[t][e]);
                    B3[(rb2 + 4 * qd + e) * STRU + (t02 + t) * 16 + nh] = pk;
                    ((unsigned*)&tp)[e] = pk;
                }
                *(uint4*)&B0[((t02 + t) * 16 + nh) * STRU + rb2 + 4 * qd] = tp;
            }
        } else if (w == 8) {
            float acc1 = 0.0f;
            #pragma unroll
            for (int m4 = 0; m4 < 16; ++m4) {
                uint4 xv = *(const uint4*)&B1[lane * STRU + 4 * m4];
                float4 b4 = *(const float4*)&Bl[4 * m4];
                acc1 += unpackf(xv.x) * b4.x + unpackf(xv.y) * b4.y
                      + unpackf(xv.z) * b4.z + unpackf(xv.w) * b4.w;
            }
            float v0 = cc * (acc1 + Bl[lane]);
            tmv[lane] = v0;
            __threadfence_block();
            float acc2 = 0.0f;
            #pragma unroll
            for (int m4 = 0; m4 < 16; ++m4) {
                uint4 xv = *(const uint4*)&B1[lane * STRU + 4 * m4];
                float4 t4 = *(const float4*)&tmv[4 * m4];
                acc2 += unpackf(xv.x) * t4.x + unpackf(xv.y) * t4.y
                      + unpackf(xv.z) * t4.z + unpackf(xv.w) * t4.w;
            }
            B4[0 * STRU + lane] = packhl(v0);        // Vt row 0 = dB
            B4[1 * STRU + lane] = packhl(acc2);      // Vt row 1 = dA*dB
        } else if (w == 9) {
            B5[lane] = packhl(Cl[lane]);             // Ut row 0 = C
        }
    }
    __syncthreads();

    // ---- ladder p=1..11: bX = X_p = dA^(2^p).
    //   w0-7 (p<11): sq -> bN rows, bNT transposed.
    //   w8-11: V-dbl (p<6) on Vt(B4) with bX; U-dbl (p>=6) on Ut(B5) with bXT.
    unsigned *bX = B3, *bXT = B0, *bN = B1, *bNT = B2;
    #pragma unroll 1
    for (int p = 1; p < 12; ++p) {
        if (w < 8) {
            if (p < 11) {
                v4f a[2]; strip_acc<2>(bX, bXT, rb2, t02, lane, a);
                #pragma unroll
                for (int t = 0; t < 2; ++t) {
                    uint4 tp;
                    #pragma unroll
                    for (int e = 0; e < 4; ++e) {
                        unsigned pk = packhl(a[t][e]);
                        bN[(rb2 + 4 * qd + e) * STRU + (t02 + t) * 16 + nh] = pk;
                        ((unsigned*)&tp)[e] = pk;
                    }
                    *(uint4*)&bNT[((t02 + t) * 16 + nh) * STRU + rb2 + 4 * qd] = tp;
                }
            }
        } else {
            const bool isV = (p < 6);
            const int  k   = 1 << (isV ? p : p - 6);
            const int  nd  = (k > 16) ? 4 : 2;
            const int  u   = w - 8;
            if (u < nd) {
                const int sr = (k > 16) ? (u >> 1) : 0;
                const int ch = (k > 16) ? (u & 1) : u;
                unsigned* Kt = isV ? B4 : B5;
                const unsigned* Mq = isV ? bX : bXT;
                v4f a[2]; strip_acc<2>(Kt, Mq, 16 * sr, 2 * ch, lane, a);
                #pragma unroll
                for (int t = 0; t < 2; ++t)
                    #pragma unroll
                    for (int e = 0; e < 4; ++e) {
                        const int j = 16 * sr + 4 * qd + e;
                        if (j < k)
                            Kt[(k + j) * STRU + (2 * ch + t) * 16 + nh] = packhl(a[t][e]);
                    }
            }
        }
        __syncthreads();
        if (p < 11) {
            unsigned* s = bX;  bX  = bN;  bN  = s;
            s = bXT; bXT = bNT; bNT = s;
        }
    }

    // ---- final (16 units): out[h][64q + r] = sum_n Ut[q][n] * Vt[r][n] ----
    {
        v4f a[1]; strip_acc<1>(B5, B4, rb1, t01, lane, a);
        float* oh = out + (size_t)h * 4096;
        #pragma unroll
        for (int e = 0; e < 4; ++e)
            oh[(rb1 + 4 * qd + e) * 64 + t01 * 16 + nh] = a[0][e];
    }
}

extern "C" void kernel_launch(void* const* d_in, const int* in_sizes, int n_in,
                              void* d_out, int out_size, void* d_ws, size_t ws_size,
                              hipStream_t stream) {
    const float* A  = (const float*)d_in[0];
    const float* B  = (const float*)d_in[1];
    const float* C  = (const float*)d_in[2];
    const float* ld = (const float*)d_in[3];
    float* out = (float*)d_out;
    const int H = in_sizes[3];   // 256 heads
    krylov_kernel<<<H, 1024, 0, stream>>>(A, B, C, ld, out);
}